// Round 3
// baseline (336.669 us; speedup 1.0000x reference)
//
#include <hip/hip_runtime.h>
#include <hip/hip_bf16.h>

#define H_  16
#define L_  8192
#define D_  64
#define MB_ 128   // query blocks (L/64)
#define NB_ 128   // kv blocks
#define TK_ 16    // top-k kv blocks per query block

typedef __bf16 bf16x8 __attribute__((ext_vector_type(8)));
typedef float  f32x4  __attribute__((ext_vector_type(4)));
typedef unsigned short u16x8 __attribute__((ext_vector_type(8)));

union BFU { __hip_bfloat16 h; unsigned short u; };

static __device__ inline unsigned short f2bfu(float f) {
  BFU c; c.h = __float2bfloat16(f); return c.u;
}
static __device__ inline float bfu2f(unsigned short u) {
  BFU c; c.u = u; return __bfloat162float(c.h);
}

// ---- module-scope scratch: immune to ws_size / 0xAA poisoning -----------
__device__ int   g_isf32;                    // 1 if inputs are float32
__device__ float g_qpool[H_ * NB_ * 64];
__device__ float g_kpool[H_ * NB_ * 64];
__device__ int   g_lut[H_ * MB_ * TK_];

// -------- phase 0: detect input dtype ------------------------------------
// bf16 N(0,1) data: every short decodes to |x| < ~6.  f32 data read as
// shorts: ~48% of low-halves decode to |x| > 100 (random exponent bits).
__global__ void sniff_kernel(const unsigned short* __restrict__ q) {
  const int lane = threadIdx.x;           // 0..63
  int cnt = 0;
  for (int i = 0; i < 64; ++i) {
    float x = bfu2f(q[lane * 64 + i]);
    if (!(fabsf(x) < 100.f)) ++cnt;       // counts NaN and huge values
  }
  for (int m = 1; m < 64; m <<= 1) cnt += __shfl_xor(cnt, m, 64);
  if (lane == 0) g_isf32 = (cnt > 64) ? 1 : 0;
}

static __device__ inline float ld_elem(const unsigned short* p, size_t idx, int isf32) {
  return isf32 ? ((const float*)p)[idx] : bfu2f(p[idx]);
}

// -------- phase 1a: block mean-pool q and k ------------------------------
__global__ void pool_kernel(const unsigned short* __restrict__ q,
                            const unsigned short* __restrict__ k) {
  const int isf32 = g_isf32;
  const int b = blockIdx.x;           // h*NB_ + n
  const int d = threadIdx.x;          // 0..63
  const size_t base = (size_t)b * 64 * D_ + d;
  float sq = 0.f, sk = 0.f;
  for (int r = 0; r < 64; ++r) {
    sq += ld_elem(q, base + (size_t)r * D_, isf32);
    sk += ld_elem(k, base + (size_t)r * D_, isf32);
  }
  g_qpool[b * 64 + d] = sq * (1.f / 64.f);
  g_kpool[b * 64 + d] = sk * (1.f / 64.f);
}

// -------- phase 1b: subtract per-head mean from pooled k -----------------
__global__ void center_kernel() {
  const int h = blockIdx.x;
  const int d = threadIdx.x;          // 0..63
  const int base = h * NB_ * 64 + d;
  float s = 0.f;
  for (int n = 0; n < NB_; ++n) s += g_kpool[base + n * 64];
  const float mean = s * (1.f / NB_);
  for (int n = 0; n < NB_; ++n) g_kpool[base + n * 64] -= mean;
}

// -------- phase 1c: pred = qpool . kpool^T, top-16 per row ---------------
__global__ void topk_kernel() {
  const int b = blockIdx.x;           // h*MB_ + m
  const int h = b >> 7;
  const int lane = threadIdx.x;       // 0..63; handles n=lane and n=lane+64
  const float4* qrow = (const float4*)(g_qpool + b * 64);
  const float4* k0 = (const float4*)(g_kpool + (h * NB_ + lane) * 64);
  const float4* k1 = (const float4*)(g_kpool + (h * NB_ + lane + 64) * 64);
  float v0 = 0.f, v1 = 0.f;
  for (int i = 0; i < 16; ++i) {
    float4 qv = qrow[i];
    float4 a = k0[i];
    float4 c = k1[i];
    v0 += qv.x * a.x + qv.y * a.y + qv.z * a.z + qv.w * a.w;
    v1 += qv.x * c.x + qv.y * c.y + qv.z * c.z + qv.w * c.w;
  }
  // iterative argmax, ties -> lower index (matches jax.lax.top_k set)
  for (int t = 0; t < TK_; ++t) {
    float bv; int bi;
    if (v0 >= v1) { bv = v0; bi = lane; } else { bv = v1; bi = lane + 64; }
    for (int mask = 1; mask < 64; mask <<= 1) {
      float ov = __shfl_xor(bv, mask, 64);
      int   oi = __shfl_xor(bi, mask, 64);
      if (ov > bv || (ov == bv && oi < bi)) { bv = ov; bi = oi; }
    }
    if (lane == 0) g_lut[b * TK_ + t] = bi;
    if (bi == lane) v0 = -3.0e38f;
    else if (bi == lane + 64) v1 = -3.0e38f;
  }
}

// convert 16 consecutive f32 to 16 bf16 shorts at dst
static __device__ inline void cvt16(const float4* src, unsigned short* dst) {
  float4 f0 = src[0], f1 = src[1], f2 = src[2], f3 = src[3];
  u16x8 s0, s1;
  s0[0] = f2bfu(f0.x); s0[1] = f2bfu(f0.y); s0[2] = f2bfu(f0.z); s0[3] = f2bfu(f0.w);
  s0[4] = f2bfu(f1.x); s0[5] = f2bfu(f1.y); s0[6] = f2bfu(f1.z); s0[7] = f2bfu(f1.w);
  s1[0] = f2bfu(f2.x); s1[1] = f2bfu(f2.y); s1[2] = f2bfu(f2.z); s1[3] = f2bfu(f2.w);
  s1[4] = f2bfu(f3.x); s1[5] = f2bfu(f3.y); s1[6] = f2bfu(f3.z); s1[7] = f2bfu(f3.w);
  *(u16x8*)dst = s0;
  *(u16x8*)(dst + 8) = s1;
}

// NaN-eating clamp: NaN -> 1e30, +-inf -> +-1e30, finite unchanged
static __device__ inline float sanef(float x) {
  return fmaxf(fminf(x, 1.0e30f), -1.0e30f);
}

// -------- phase 2: sparse flash attention over selected KV blocks --------
__global__ __launch_bounds__(256, 2)
void attn_kernel(const unsigned short* __restrict__ q,
                 const unsigned short* __restrict__ k,
                 const unsigned short* __restrict__ v,
                 void* __restrict__ outv) {
  __shared__ __align__(16) unsigned short Qs[64 * 64];      // [qrow][d]
  __shared__ __align__(16) unsigned short Ks[64 * 64];      // [kk][d]
  __shared__ __align__(16) unsigned short Vt[64 * 64];      // [d][kk] (transposed)
  __shared__ __align__(16) unsigned short Pw[4][16 * 64];   // per-wave P [qrow16][kk]

  const int isf32 = g_isf32;
  const int blk = blockIdx.x;          // h*MB_ + m
  const int h = blk >> 7, m = blk & 127;
  const int t = threadIdx.x;
  const int w = t >> 6;                // wave id: q rows 16w..16w+15
  const int lane = t & 63;
  const int l16 = lane & 15, quad = lane >> 4;

  const size_t qoff = ((size_t)h * L_ + (size_t)m * 64) * D_;
  if (!isf32) {
    const unsigned short* qg = q + qoff;
    *(u16x8*)(Qs + t * 8)        = *(const u16x8*)(qg + t * 8);
    *(u16x8*)(Qs + 2048 + t * 8) = *(const u16x8*)(qg + 2048 + t * 8);
  } else {
    const float4* qf = (const float4*)((const float*)q + qoff) + t * 4;
    cvt16(qf, Qs + t * 16);
  }
  __syncthreads();

  // Q A-fragments (fixed for whole kernel): A[m=l16][k=quad*8+j]
  const bf16x8 aq0 = *(const bf16x8*)&Qs[(16 * w + l16) * 64 + quad * 8];
  const bf16x8 aq1 = *(const bf16x8*)&Qs[(16 * w + l16) * 64 + 32 + quad * 8];

  f32x4 o[4];
  #pragma unroll
  for (int n4 = 0; n4 < 4; ++n4) o[n4] = (f32x4){0.f, 0.f, 0.f, 0.f};
  float mrow[4] = {-1e30f, -1e30f, -1e30f, -1e30f};
  float lrow[4] = {0.f, 0.f, 0.f, 0.f};

  const int* my_lut = g_lut + blk * TK_;
  const int vr = t >> 2;              // V row handled by this thread
  const int vc = (t & 3) * 16;        // V col chunk start

  const float cs = 0.18033688011112042f;  // (1/sqrt(64)) * log2(e)

  for (int j = 0; j < TK_; ++j) {
    const int kb = my_lut[j] & 127;   // defensive: garbage lut -> in-range
    const size_t koff = ((size_t)h * L_ + (size_t)kb * 64) * D_;

    if (!isf32) {
      const unsigned short* kg = k + koff;
      const unsigned short* vg = v + koff;
      *(u16x8*)(Ks + t * 8)        = *(const u16x8*)(kg + t * 8);
      *(u16x8*)(Ks + 2048 + t * 8) = *(const u16x8*)(kg + 2048 + t * 8);
      u16x8 x0 = *(const u16x8*)(vg + vr * 64 + vc);
      u16x8 x1 = *(const u16x8*)(vg + vr * 64 + vc + 8);
      #pragma unroll
      for (int i = 0; i < 8; ++i) {
        Vt[(vc + i) * 64 + vr]     = x0[i];
        Vt[(vc + 8 + i) * 64 + vr] = x1[i];
      }
    } else {
      const float* kg32 = (const float*)k + koff;
      const float* vg32 = (const float*)v + koff;
      cvt16((const float4*)kg32 + t * 4, Ks + t * 16);
      const float4* vf = (const float4*)(vg32 + vr * 64 + vc);
      float4 f0 = vf[0], f1 = vf[1], f2 = vf[2], f3 = vf[3];
      float tmp[16] = {f0.x, f0.y, f0.z, f0.w, f1.x, f1.y, f1.z, f1.w,
                       f2.x, f2.y, f2.z, f2.w, f3.x, f3.y, f3.z, f3.w};
      #pragma unroll
      for (int i = 0; i < 16; ++i)
        Vt[(vc + i) * 64 + vr] = f2bfu(tmp[i]);
    }
    __syncthreads();

    // ---- S = Q K^T : per wave 16x64, 4 n-tiles x 2 k-steps -------------
    f32x4 acc[4];
    #pragma unroll
    for (int n4 = 0; n4 < 4; ++n4) {
      bf16x8 b0 = *(const bf16x8*)&Ks[(n4 * 16 + l16) * 64 + quad * 8];
      bf16x8 b1 = *(const bf16x8*)&Ks[(n4 * 16 + l16) * 64 + 32 + quad * 8];
      f32x4 z = (f32x4){0.f, 0.f, 0.f, 0.f};
      z = __builtin_amdgcn_mfma_f32_16x16x32_bf16(aq0, b0, z, 0, 0, 0);
      z = __builtin_amdgcn_mfma_f32_16x16x32_bf16(aq1, b1, z, 0, 0, 0);
      acc[n4] = z;
    }

    // ---- online softmax in C/D layout: row = quad*4+r, col = n4*16+l16 -
    float p[4][4];
    #pragma unroll
    for (int r = 0; r < 4; ++r) {
      float x0r = sanef(acc[0][r] * cs), x1r = sanef(acc[1][r] * cs);
      float x2r = sanef(acc[2][r] * cs), x3r = sanef(acc[3][r] * cs);
      float mx = fmaxf(fmaxf(x0r, x1r), fmaxf(x2r, x3r));
      #pragma unroll
      for (int mask = 1; mask < 16; mask <<= 1)
        mx = fmaxf(mx, __shfl_xor(mx, mask, 64));
      const float nm = fmaxf(mrow[r], mx);
      const float alpha = exp2f(mrow[r] - nm);
      mrow[r] = nm;
      p[0][r] = exp2f(x0r - nm); p[1][r] = exp2f(x1r - nm);
      p[2][r] = exp2f(x2r - nm); p[3][r] = exp2f(x3r - nm);
      float rs = p[0][r] + p[1][r] + p[2][r] + p[3][r];
      #pragma unroll
      for (int mask = 1; mask < 16; mask <<= 1)
        rs += __shfl_xor(rs, mask, 64);
      lrow[r] = lrow[r] * alpha + rs;
      #pragma unroll
      for (int n4 = 0; n4 < 4; ++n4) o[n4][r] *= alpha;
    }

    // ---- P through LDS: C/D layout -> A-operand layout ------------------
    unsigned short* pw = &Pw[w][0];
    #pragma unroll
    for (int n4 = 0; n4 < 4; ++n4)
      #pragma unroll
      for (int r = 0; r < 4; ++r)
        pw[(quad * 4 + r) * 64 + n4 * 16 + l16] = f2bfu(p[n4][r]);

    __syncthreads();   // order P writes before P reads

    const bf16x8 pa0 = *(const bf16x8*)&pw[l16 * 64 + quad * 8];
    const bf16x8 pa1 = *(const bf16x8*)&pw[l16 * 64 + 32 + quad * 8];

    // ---- O += P V : B-operand from transposed Vt ------------------------
    #pragma unroll
    for (int n4 = 0; n4 < 4; ++n4) {
      bf16x8 v0f = *(const bf16x8*)&Vt[(n4 * 16 + l16) * 64 + quad * 8];
      bf16x8 v1f = *(const bf16x8*)&Vt[(n4 * 16 + l16) * 64 + 32 + quad * 8];
      o[n4] = __builtin_amdgcn_mfma_f32_16x16x32_bf16(pa0, v0f, o[n4], 0, 0, 0);
      o[n4] = __builtin_amdgcn_mfma_f32_16x16x32_bf16(pa1, v1f, o[n4], 0, 0, 0);
    }
    __syncthreads();   // all waves done with Ks/Vt before next staging
  }

  // ---- epilogue: divide by row sum, store ---------------------------------
  const size_t obase = ((size_t)h * L_ + (size_t)m * 64) * D_;
  #pragma unroll
  for (int n4 = 0; n4 < 4; ++n4) {
    #pragma unroll
    for (int r = 0; r < 4; ++r) {
      const int qrow = 16 * w + quad * 4 + r;
      const float val = o[n4][r] / lrow[r];
      const size_t idx = obase + (size_t)qrow * 64 + n4 * 16 + l16;
      if (!isf32) ((unsigned short*)outv)[idx] = f2bfu(val);
      else        ((float*)outv)[idx] = val;
    }
  }
}

extern "C" void kernel_launch(void* const* d_in, const int* in_sizes, int n_in,
                              void* d_out, int out_size, void* d_ws, size_t ws_size,
                              hipStream_t stream) {
  const unsigned short* q = (const unsigned short*)d_in[0];
  const unsigned short* k = (const unsigned short*)d_in[1];
  const unsigned short* v = (const unsigned short*)d_in[2];

  sniff_kernel<<<1, 64, 0, stream>>>(q);
  pool_kernel<<<H_ * NB_, 64, 0, stream>>>(q, k);
  center_kernel<<<H_, 64, 0, stream>>>();
  topk_kernel<<<H_ * MB_, 64, 0, stream>>>();
  attn_kernel<<<H_ * MB_, 256, 0, stream>>>(q, k, v, d_out);
}

// Round 7
// 321.987 us; speedup vs baseline: 1.0456x; 1.0456x over previous
//
#include <hip/hip_runtime.h>
#include <hip/hip_bf16.h>

// Inputs q,k,v are FLOAT32 (reference dtypes; confirmed R2 WRITE_SIZE=33.6MB
// = f32 output, and only the sniffer-equipped f32-path kernel ever passed).
// Output is FLOAT32.

#define H_  16
#define L_  8192
#define D_  64
#define MB_ 128   // query blocks (L/64)
#define NB_ 128   // kv blocks
#define TK_ 16    // top-k kv blocks per query block
#define PST 72    // Pw row stride (144 B, 16B-aligned, breaks 8-way conflicts)

typedef __bf16 bf16x8 __attribute__((ext_vector_type(8)));
typedef float  f32x4  __attribute__((ext_vector_type(4)));
typedef unsigned short u16x8 __attribute__((ext_vector_type(8)));

union BFU { __hip_bfloat16 h; unsigned short u; };

static __device__ inline unsigned short f2bfu(float f) {
  BFU c; c.h = __float2bfloat16(f); return c.u;
}

// module-scope scratch (round-3 lesson: never trust d_ws for the lut)
__device__ unsigned short g_kb[(size_t)H_ * L_ * D_];   // k as bf16, 16.8 MB
__device__ unsigned short g_vb[(size_t)H_ * L_ * D_];   // v as bf16, 16.8 MB
__device__ float g_qpool[H_ * NB_ * 64];
__device__ float g_kpool[H_ * NB_ * 64];
__device__ int   g_lut[H_ * MB_ * TK_];

// -------- phase 0: one-time f32 -> bf16 conversion of k and v ------------
__global__ void convert_kernel(const float* __restrict__ k,
                               const float* __restrict__ v) {
  const size_t N = (size_t)H_ * L_ * D_;
  const size_t stride = (size_t)gridDim.x * blockDim.x * 8;
  for (size_t i = ((size_t)blockIdx.x * blockDim.x + threadIdx.x) * 8;
       i < N; i += stride) {
    float4 a0 = *(const float4*)(k + i), a1 = *(const float4*)(k + i + 4);
    float4 b0 = *(const float4*)(v + i), b1 = *(const float4*)(v + i + 4);
    u16x8 ks, vs;
    ks[0] = f2bfu(a0.x); ks[1] = f2bfu(a0.y); ks[2] = f2bfu(a0.z); ks[3] = f2bfu(a0.w);
    ks[4] = f2bfu(a1.x); ks[5] = f2bfu(a1.y); ks[6] = f2bfu(a1.z); ks[7] = f2bfu(a1.w);
    vs[0] = f2bfu(b0.x); vs[1] = f2bfu(b0.y); vs[2] = f2bfu(b0.z); vs[3] = f2bfu(b0.w);
    vs[4] = f2bfu(b1.x); vs[5] = f2bfu(b1.y); vs[6] = f2bfu(b1.z); vs[7] = f2bfu(b1.w);
    *(u16x8*)(g_kb + i) = ks;
    *(u16x8*)(g_vb + i) = vs;
  }
}

// -------- phase 1a: block mean-pool q and k (f32, R2's exact sum order) --
__global__ void pool_kernel(const float* __restrict__ q,
                            const float* __restrict__ k) {
  const int b = blockIdx.x;           // h*NB_ + n
  const int d = threadIdx.x;          // 0..63
  const size_t base = (size_t)b * 64 * D_ + d;
  float sq = 0.f, sk = 0.f;
  for (int r = 0; r < 64; ++r) {
    sq += q[base + (size_t)r * D_];
    sk += k[base + (size_t)r * D_];
  }
  g_qpool[b * 64 + d] = sq * (1.f / 64.f);
  g_kpool[b * 64 + d] = sk * (1.f / 64.f);
}

// -------- phase 1b: subtract per-head mean from pooled k (parallel) ------
__global__ void center_kernel() {
  __shared__ float part[4][64];
  const int h = blockIdx.x;
  const int d = threadIdx.x & 63;
  const int s = threadIdx.x >> 6;     // 0..3, each covers 32 n's
  const int base = h * NB_ * 64 + d;
  float sum = 0.f;
  for (int n = s * 32; n < s * 32 + 32; ++n) sum += g_kpool[base + n * 64];
  part[s][d] = sum;
  __syncthreads();
  const float mean = (part[0][d] + part[1][d] + part[2][d] + part[3][d]) * (1.f / NB_);
  for (int n = s * 32; n < s * 32 + 32; ++n) g_kpool[base + n * 64] -= mean;
}

// -------- phase 1c: pred = qpool . kpool^T, top-16 per row ---------------
__global__ void topk_kernel() {
  const int b = blockIdx.x;           // h*MB_ + m
  const int h = b >> 7;
  const int lane = threadIdx.x;       // 0..63; handles n=lane and n=lane+64
  const float4* qrow = (const float4*)(g_qpool + b * 64);
  const float4* k0 = (const float4*)(g_kpool + (h * NB_ + lane) * 64);
  const float4* k1 = (const float4*)(g_kpool + (h * NB_ + lane + 64) * 64);
  float v0 = 0.f, v1 = 0.f;
  for (int i = 0; i < 16; ++i) {
    float4 qv = qrow[i];
    float4 a = k0[i];
    float4 c = k1[i];
    v0 += qv.x * a.x + qv.y * a.y + qv.z * a.z + qv.w * a.w;
    v1 += qv.x * c.x + qv.y * c.y + qv.z * c.z + qv.w * c.w;
  }
  // iterative argmax, ties -> lower index (matches jax.lax.top_k set)
  for (int t = 0; t < TK_; ++t) {
    float bv; int bi;
    if (v0 >= v1) { bv = v0; bi = lane; } else { bv = v1; bi = lane + 64; }
    for (int mask = 1; mask < 64; mask <<= 1) {
      float ov = __shfl_xor(bv, mask, 64);
      int   oi = __shfl_xor(bi, mask, 64);
      if (ov > bv || (ov == bv && oi < bi)) { bv = ov; bi = oi; }
    }
    if (lane == 0) g_lut[b * TK_ + t] = bi;
    if (bi == lane) v0 = -3.0e38f;
    else if (bi == lane + 64) v1 = -3.0e38f;
  }
}

// convert 16 consecutive f32 to 16 bf16 shorts at dst (R2-proven helper)
static __device__ inline void cvt16(const float4* src, unsigned short* dst) {
  float4 f0 = src[0], f1 = src[1], f2 = src[2], f3 = src[3];
  u16x8 s0, s1;
  s0[0] = f2bfu(f0.x); s0[1] = f2bfu(f0.y); s0[2] = f2bfu(f0.z); s0[3] = f2bfu(f0.w);
  s0[4] = f2bfu(f1.x); s0[5] = f2bfu(f1.y); s0[6] = f2bfu(f1.z); s0[7] = f2bfu(f1.w);
  s1[0] = f2bfu(f2.x); s1[1] = f2bfu(f2.y); s1[2] = f2bfu(f2.z); s1[3] = f2bfu(f2.w);
  s1[4] = f2bfu(f3.x); s1[5] = f2bfu(f3.y); s1[6] = f2bfu(f3.z); s1[7] = f2bfu(f3.w);
  *(u16x8*)dst = s0;
  *(u16x8*)(dst + 8) = s1;
}

// -------- phase 2: sparse flash attention over selected KV blocks --------
__global__ __launch_bounds__(256, 4)
void attn_kernel(const float* __restrict__ q,
                 float* __restrict__ out) {
  __shared__ __align__(16) unsigned short Qs[64 * 64];      // [qrow][d]
  __shared__ __align__(16) unsigned short Ks[64 * 64];      // [kk][d]
  __shared__ __align__(16) unsigned short Vt[64 * 64];      // [d][kk] transposed
  __shared__ __align__(16) unsigned short Pw[4][16 * PST];  // per-wave P

  const int blk = blockIdx.x;
  // XCD swizzle: h = blk&15 -> blk%8 == h%8; 2 heads/XCD, K+V bf16 = 4 MB = L2
  const int h = blk & 15, m = blk >> 4;
  const int t = threadIdx.x;
  const int w = t >> 6;                // wave id: q rows 16w..16w+15
  const int lane = t & 63;
  const int l16 = lane & 15, quad = lane >> 4;

  // stage Q: f32 load + convert, once per block
  const float* qg = q + ((size_t)h * L_ + (size_t)m * 64) * D_;
  cvt16((const float4*)qg + t * 4, Qs + t * 16);
  __syncthreads();

  // Q A-fragments (fixed): A[m=l16][k=quad*8+j]
  const bf16x8 aq0 = *(const bf16x8*)&Qs[(16 * w + l16) * 64 + quad * 8];
  const bf16x8 aq1 = *(const bf16x8*)&Qs[(16 * w + l16) * 64 + 32 + quad * 8];

  f32x4 o[4];
  #pragma unroll
  for (int n4 = 0; n4 < 4; ++n4) o[n4] = (f32x4){0.f, 0.f, 0.f, 0.f};
  float mrow[4] = {-1e30f, -1e30f, -1e30f, -1e30f};
  float lrow[4] = {0.f, 0.f, 0.f, 0.f};

  const int* my_lut = g_lut + (h * MB_ + m) * TK_;   // topk index is h*MB_+m
  const float cs = 0.18033688011112042f;  // (1/sqrt(64)) * log2(e)

  // prefetch KV block 0 (bf16 from converted arrays)
  const int kb0 = my_lut[0] & 127;
  const size_t koff0 = ((size_t)h * L_ + (size_t)kb0 * 64) * D_;
  u16x8 kx0 = *(const u16x8*)(g_kb + koff0 + t * 8);
  u16x8 kx1 = *(const u16x8*)(g_kb + koff0 + 2048 + t * 8);
  // V: lane owns kk-row `lane`, cols w*16..w*16+15
  u16x8 vx0 = *(const u16x8*)(g_vb + koff0 + (size_t)lane * 64 + w * 16);
  u16x8 vx1 = *(const u16x8*)(g_vb + koff0 + (size_t)lane * 64 + w * 16 + 8);

  for (int j = 0; j < TK_; ++j) {
    // stage K (b128 writes)
    *(u16x8*)(Ks + t * 8)        = kx0;
    *(u16x8*)(Ks + 2048 + t * 8) = kx1;
    // stage V transposed: bank = (lane>>1)&31 -> 2 lanes/bank = free
    #pragma unroll
    for (int i = 0; i < 8; ++i) {
      Vt[(w * 16 + i) * 64 + lane]     = vx0[i];
      Vt[(w * 16 + 8 + i) * 64 + lane] = vx1[i];
    }
    __syncthreads();                   // staging visible to all waves

    // prefetch next KV block; latency hides under compute below
    if (j + 1 < TK_) {
      const int kb = my_lut[j + 1] & 127;
      const size_t koff = ((size_t)h * L_ + (size_t)kb * 64) * D_;
      kx0 = *(const u16x8*)(g_kb + koff + t * 8);
      kx1 = *(const u16x8*)(g_kb + koff + 2048 + t * 8);
      vx0 = *(const u16x8*)(g_vb + koff + (size_t)lane * 64 + w * 16);
      vx1 = *(const u16x8*)(g_vb + koff + (size_t)lane * 64 + w * 16 + 8);
    }

    // ---- S = Q K^T : per wave 16x64 --------------------------------------
    f32x4 acc[4];
    #pragma unroll
    for (int n4 = 0; n4 < 4; ++n4) {
      bf16x8 b0 = *(const bf16x8*)&Ks[(n4 * 16 + l16) * 64 + quad * 8];
      bf16x8 b1 = *(const bf16x8*)&Ks[(n4 * 16 + l16) * 64 + 32 + quad * 8];
      f32x4 z = (f32x4){0.f, 0.f, 0.f, 0.f};
      z = __builtin_amdgcn_mfma_f32_16x16x32_bf16(aq0, b0, z, 0, 0, 0);
      z = __builtin_amdgcn_mfma_f32_16x16x32_bf16(aq1, b1, z, 0, 0, 0);
      acc[n4] = z;
    }

    // ---- online softmax (C-layout: row=quad*4+r, col=n4*16+l16) ----------
    float p[4][4];
    #pragma unroll
    for (int r = 0; r < 4; ++r) {
      float x0r = acc[0][r] * cs, x1r = acc[1][r] * cs;
      float x2r = acc[2][r] * cs, x3r = acc[3][r] * cs;
      float mx = fmaxf(fmaxf(x0r, x1r), fmaxf(x2r, x3r));
      #pragma unroll
      for (int mask = 1; mask < 16; mask <<= 1)
        mx = fmaxf(mx, __shfl_xor(mx, mask, 64));
      const float nm = fmaxf(mrow[r], mx);
      const float alpha = exp2f(mrow[r] - nm);
      mrow[r] = nm;
      p[0][r] = exp2f(x0r - nm); p[1][r] = exp2f(x1r - nm);
      p[2][r] = exp2f(x2r - nm); p[3][r] = exp2f(x3r - nm);
      float rs = p[0][r] + p[1][r] + p[2][r] + p[3][r];
      #pragma unroll
      for (int mask = 1; mask < 16; mask <<= 1)
        rs += __shfl_xor(rs, mask, 64);
      lrow[r] = lrow[r] * alpha + rs;
      #pragma unroll
      for (int n4 = 0; n4 < 4; ++n4) o[n4][r] *= alpha;
    }

    // ---- P through per-wave LDS: C-layout -> A-operand layout ------------
    unsigned short* pw = &Pw[w][0];
    #pragma unroll
    for (int n4 = 0; n4 < 4; ++n4)
      #pragma unroll
      for (int r = 0; r < 4; ++r)
        pw[(quad * 4 + r) * PST + n4 * 16 + l16] = f2bfu(p[n4][r]);

    __syncthreads();                   // order Pw writes before reads

    const bf16x8 pa0 = *(const bf16x8*)&pw[l16 * PST + quad * 8];
    const bf16x8 pa1 = *(const bf16x8*)&pw[l16 * PST + 32 + quad * 8];

    // ---- O += P V (B from Vt) --------------------------------------------
    #pragma unroll
    for (int n4 = 0; n4 < 4; ++n4) {
      bf16x8 v0f = *(const bf16x8*)&Vt[(n4 * 16 + l16) * 64 + quad * 8];
      bf16x8 v1f = *(const bf16x8*)&Vt[(n4 * 16 + l16) * 64 + 32 + quad * 8];
      o[n4] = __builtin_amdgcn_mfma_f32_16x16x32_bf16(pa0, v0f, o[n4], 0, 0, 0);
      o[n4] = __builtin_amdgcn_mfma_f32_16x16x32_bf16(pa1, v1f, o[n4], 0, 0, 0);
    }
    __syncthreads();                   // all waves done with Ks/Vt/Pw
  }

  // ---- epilogue: divide by row sum, store f32 ----------------------------
  const size_t obase = ((size_t)h * L_ + (size_t)m * 64) * D_;
  #pragma unroll
  for (int n4 = 0; n4 < 4; ++n4) {
    #pragma unroll
    for (int r = 0; r < 4; ++r) {
      const int qrow = 16 * w + quad * 4 + r;
      out[obase + (size_t)qrow * 64 + n4 * 16 + l16] = o[n4][r] / lrow[r];
    }
  }
}

extern "C" void kernel_launch(void* const* d_in, const int* in_sizes, int n_in,
                              void* d_out, int out_size, void* d_ws, size_t ws_size,
                              hipStream_t stream) {
  const float* q = (const float*)d_in[0];
  const float* k = (const float*)d_in[1];
  const float* v = (const float*)d_in[2];
  float* out = (float*)d_out;

  convert_kernel<<<1024, 256, 0, stream>>>(k, v);
  pool_kernel<<<H_ * NB_, 64, 0, stream>>>(q, k);
  center_kernel<<<H_, 256, 0, stream>>>();
  topk_kernel<<<H_ * MB_, 64, 0, stream>>>();
  attn_kernel<<<H_ * MB_, 256, 0, stream>>>(q, out);
}

// Round 8
// 299.405 us; speedup vs baseline: 1.1245x; 1.0754x over previous
//
#include <hip/hip_runtime.h>
#include <hip/hip_bf16.h>

// Inputs q,k,v are FLOAT32; output FLOAT32 (confirmed R2/R7).

#define H_  16
#define L_  8192
#define D_  64
#define MB_ 128   // query blocks (L/64)
#define NB_ 128   // kv blocks
#define TK_ 16    // top-k kv blocks per query block
#define ST_ 72    // LDS row stride (144 B: 16B-aligned, conflict-free b128)
#define PST 72    // Pw row stride

typedef __bf16 bf16x8 __attribute__((ext_vector_type(8)));
typedef float  f32x4  __attribute__((ext_vector_type(4)));
typedef unsigned short u16x8 __attribute__((ext_vector_type(8)));

union BFU { __hip_bfloat16 h; unsigned short u; };

static __device__ inline unsigned short f2bfu(float f) {
  BFU c; c.h = __float2bfloat16(f); return c.u;
}

// module-scope scratch (round-3 lesson: never trust d_ws for the lut)
__device__ unsigned short g_qb[(size_t)H_ * L_ * D_];   // q as bf16
__device__ unsigned short g_kb[(size_t)H_ * L_ * D_];   // k as bf16
__device__ unsigned short g_vb[(size_t)H_ * L_ * D_];   // v as bf16
__device__ float g_qpool[H_ * NB_ * 64];
__device__ float g_kpool[H_ * NB_ * 64];
__device__ int   g_lut[H_ * MB_ * TK_];

static __device__ inline void cvt8_2(const float4& f0, const float4& f1,
                                     unsigned short* dst) {
  u16x8 s;
  s[0] = f2bfu(f0.x); s[1] = f2bfu(f0.y); s[2] = f2bfu(f0.z); s[3] = f2bfu(f0.w);
  s[4] = f2bfu(f1.x); s[5] = f2bfu(f1.y); s[6] = f2bfu(f1.z); s[7] = f2bfu(f1.w);
  *(u16x8*)dst = s;
}

// -------- phase 1: fused f32->bf16 convert (q,k,v) + block mean-pool -----
__global__ __launch_bounds__(256)
void fusedpool_kernel(const float* __restrict__ q,
                      const float* __restrict__ k,
                      const float* __restrict__ v) {
  __shared__ float qt[64 * 64];
  __shared__ float kt[64 * 64];
  __shared__ float pq[4][64], pk[4][64];

  const int b = blockIdx.x;           // h*NB_ + n
  const int t = threadIdx.x;
  const int r = t >> 2, c = (t & 3) * 16;
  const size_t base = (size_t)b * 4096 + r * 64 + c;

  float4 qf0 = *(const float4*)(q + base),      qf1 = *(const float4*)(q + base + 4);
  float4 qf2 = *(const float4*)(q + base + 8),  qf3 = *(const float4*)(q + base + 12);
  float4 kf0 = *(const float4*)(k + base),      kf1 = *(const float4*)(k + base + 4);
  float4 kf2 = *(const float4*)(k + base + 8),  kf3 = *(const float4*)(k + base + 12);
  float4 vf0 = *(const float4*)(v + base),      vf1 = *(const float4*)(v + base + 4);
  float4 vf2 = *(const float4*)(v + base + 8),  vf3 = *(const float4*)(v + base + 12);

  cvt8_2(qf0, qf1, g_qb + base);  cvt8_2(qf2, qf3, g_qb + base + 8);
  cvt8_2(kf0, kf1, g_kb + base);  cvt8_2(kf2, kf3, g_kb + base + 8);
  cvt8_2(vf0, vf1, g_vb + base);  cvt8_2(vf2, vf3, g_vb + base + 8);

  // stash f32 q,k tiles for exact pooling
  *(float4*)(qt + r * 64 + c)      = qf0; *(float4*)(qt + r * 64 + c + 4)  = qf1;
  *(float4*)(qt + r * 64 + c + 8)  = qf2; *(float4*)(qt + r * 64 + c + 12) = qf3;
  *(float4*)(kt + r * 64 + c)      = kf0; *(float4*)(kt + r * 64 + c + 4)  = kf1;
  *(float4*)(kt + r * 64 + c + 8)  = kf2; *(float4*)(kt + r * 64 + c + 12) = kf3;
  __syncthreads();

  const int col = t & 63, g = t >> 6;
  float sq = 0.f, sk = 0.f;
  for (int rr = g * 16; rr < g * 16 + 16; ++rr) {
    sq += qt[rr * 64 + col];
    sk += kt[rr * 64 + col];
  }
  pq[g][col] = sq; pk[g][col] = sk;
  __syncthreads();
  if (t < 64) {
    g_qpool[b * 64 + t] = (pq[0][t] + pq[1][t] + pq[2][t] + pq[3][t]) * (1.f / 64.f);
    g_kpool[b * 64 + t] = (pk[0][t] + pk[1][t] + pk[2][t] + pk[3][t]) * (1.f / 64.f);
  }
}

// -------- phase 1b: subtract per-head mean from pooled k -----------------
__global__ void center_kernel() {
  __shared__ float part[4][64];
  const int h = blockIdx.x;
  const int d = threadIdx.x & 63;
  const int s = threadIdx.x >> 6;     // 0..3, each covers 32 n's
  const int base = h * NB_ * 64 + d;
  float sum = 0.f;
  for (int n = s * 32; n < s * 32 + 32; ++n) sum += g_kpool[base + n * 64];
  part[s][d] = sum;
  __syncthreads();
  const float mean = (part[0][d] + part[1][d] + part[2][d] + part[3][d]) * (1.f / NB_);
  for (int n = s * 32; n < s * 32 + 32; ++n) g_kpool[base + n * 64] -= mean;
}

// -------- phase 1c: pred = qpool . kpool^T, top-16 per row ---------------
__global__ void topk_kernel() {
  const int b = blockIdx.x;           // h*MB_ + m
  const int h = b >> 7;
  const int lane = threadIdx.x;       // 0..63; handles n=lane and n=lane+64
  const float4* qrow = (const float4*)(g_qpool + b * 64);
  const float4* k0 = (const float4*)(g_kpool + (h * NB_ + lane) * 64);
  const float4* k1 = (const float4*)(g_kpool + (h * NB_ + lane + 64) * 64);
  float v0 = 0.f, v1 = 0.f;
  for (int i = 0; i < 16; ++i) {
    float4 qv = qrow[i];
    float4 a = k0[i];
    float4 c = k1[i];
    v0 += qv.x * a.x + qv.y * a.y + qv.z * a.z + qv.w * a.w;
    v1 += qv.x * c.x + qv.y * c.y + qv.z * c.z + qv.w * c.w;
  }
  // iterative argmax, ties -> lower index (matches jax.lax.top_k set)
  for (int t = 0; t < TK_; ++t) {
    float bv; int bi;
    if (v0 >= v1) { bv = v0; bi = lane; } else { bv = v1; bi = lane + 64; }
    for (int mask = 1; mask < 64; mask <<= 1) {
      float ov = __shfl_xor(bv, mask, 64);
      int   oi = __shfl_xor(bi, mask, 64);
      if (ov > bv || (ov == bv && oi < bi)) { bv = ov; bi = oi; }
    }
    if (lane == 0) g_lut[b * TK_ + t] = bi;
    if (bi == lane) v0 = -3.0e38f;
    else if (bi == lane + 64) v1 = -3.0e38f;
  }
}

// -------- phase 2: sparse flash attention over selected KV blocks --------
__global__ __launch_bounds__(256, 4)
void attn_kernel(float* __restrict__ out) {
  __shared__ __align__(16) unsigned short Qs[64 * ST_];     // [qrow][d] padded
  __shared__ __align__(16) unsigned short Ks[64 * ST_];     // [kk][d] padded
  __shared__ __align__(16) unsigned short Vt[64 * ST_];     // [d][kk] padded
  __shared__ __align__(16) unsigned short Pw[4][16 * PST];  // per-wave P

  const int blk = blockIdx.x;
  // XCD swizzle: h = blk&15 -> blk%8 == h%8; 2 heads/XCD, K+V bf16 = 4 MB = L2
  const int h = blk & 15, m = blk >> 4;
  const int t = threadIdx.x;
  const int w = t >> 6;                // wave id: q rows 16w..16w+15
  const int lane = t & 63;
  const int l16 = lane & 15, quad = lane >> 4;
  const int srow = t >> 3, scol = (t & 7) * 8;   // staging row/col for b128

  // stage Q (bf16, pre-converted): padded rows, conflict-free
  const unsigned short* qg = g_qb + ((size_t)h * L_ + (size_t)m * 64) * D_;
  *(u16x8*)(Qs + srow * ST_ + scol)        = *(const u16x8*)(qg + t * 8);
  *(u16x8*)(Qs + (32 + srow) * ST_ + scol) = *(const u16x8*)(qg + 2048 + t * 8);
  __syncthreads();

  // Q A-fragments (fixed): A[m=l16][k=quad*8+j]; stride-72 rows -> bank
  // (4*l16+4*quad)%32, uniform = b128 floor (round-7 conflict fix)
  const bf16x8 aq0 = *(const bf16x8*)&Qs[(16 * w + l16) * ST_ + quad * 8];
  const bf16x8 aq1 = *(const bf16x8*)&Qs[(16 * w + l16) * ST_ + 32 + quad * 8];

  f32x4 o[4];
  #pragma unroll
  for (int n4 = 0; n4 < 4; ++n4) o[n4] = (f32x4){0.f, 0.f, 0.f, 0.f};
  float mrow[4] = {-1e30f, -1e30f, -1e30f, -1e30f};
  float lrow[4] = {0.f, 0.f, 0.f, 0.f};

  const int* my_lut = g_lut + (h * MB_ + m) * TK_;   // topk index is h*MB_+m
  const float cs = 0.18033688011112042f;  // (1/sqrt(64)) * log2(e)

  // prefetch KV block 0
  const int kb0 = my_lut[0] & 127;
  const size_t koff0 = ((size_t)h * L_ + (size_t)kb0 * 64) * D_;
  u16x8 kx0 = *(const u16x8*)(g_kb + koff0 + t * 8);
  u16x8 kx1 = *(const u16x8*)(g_kb + koff0 + 2048 + t * 8);
  u16x8 vx0 = *(const u16x8*)(g_vb + koff0 + (size_t)lane * 64 + w * 16);
  u16x8 vx1 = *(const u16x8*)(g_vb + koff0 + (size_t)lane * 64 + w * 16 + 8);

  for (int j = 0; j < TK_; ++j) {
    // stage K (b128 writes, padded rows)
    *(u16x8*)(Ks + srow * ST_ + scol)        = kx0;
    *(u16x8*)(Ks + (32 + srow) * ST_ + scol) = kx1;
    // stage V transposed: bank = (lane>>1)&31 -> 2-way = free
    #pragma unroll
    for (int i = 0; i < 8; ++i) {
      Vt[(w * 16 + i) * ST_ + lane]     = vx0[i];
      Vt[(w * 16 + 8 + i) * ST_ + lane] = vx1[i];
    }
    __syncthreads();                   // staging visible to all waves

    // prefetch next KV block; latency hides under compute below
    if (j + 1 < TK_) {
      const int kb = my_lut[j + 1] & 127;
      const size_t koff = ((size_t)h * L_ + (size_t)kb * 64) * D_;
      kx0 = *(const u16x8*)(g_kb + koff + t * 8);
      kx1 = *(const u16x8*)(g_kb + koff + 2048 + t * 8);
      vx0 = *(const u16x8*)(g_vb + koff + (size_t)lane * 64 + w * 16);
      vx1 = *(const u16x8*)(g_vb + koff + (size_t)lane * 64 + w * 16 + 8);
    }

    // ---- S = Q K^T : per wave 16x64 --------------------------------------
    f32x4 acc[4];
    #pragma unroll
    for (int n4 = 0; n4 < 4; ++n4) {
      bf16x8 b0 = *(const bf16x8*)&Ks[(n4 * 16 + l16) * ST_ + quad * 8];
      bf16x8 b1 = *(const bf16x8*)&Ks[(n4 * 16 + l16) * ST_ + 32 + quad * 8];
      f32x4 z = (f32x4){0.f, 0.f, 0.f, 0.f};
      z = __builtin_amdgcn_mfma_f32_16x16x32_bf16(aq0, b0, z, 0, 0, 0);
      z = __builtin_amdgcn_mfma_f32_16x16x32_bf16(aq1, b1, z, 0, 0, 0);
      acc[n4] = z;
    }

    // ---- online softmax (C-layout: row=quad*4+r, col=n4*16+l16) ----------
    float p[4][4];
    #pragma unroll
    for (int r = 0; r < 4; ++r) {
      float x0r = acc[0][r] * cs, x1r = acc[1][r] * cs;
      float x2r = acc[2][r] * cs, x3r = acc[3][r] * cs;
      float mx = fmaxf(fmaxf(x0r, x1r), fmaxf(x2r, x3r));
      #pragma unroll
      for (int mask = 1; mask < 16; mask <<= 1)
        mx = fmaxf(mx, __shfl_xor(mx, mask, 64));
      const float nm = fmaxf(mrow[r], mx);
      const float alpha = exp2f(mrow[r] - nm);
      mrow[r] = nm;
      p[0][r] = exp2f(x0r - nm); p[1][r] = exp2f(x1r - nm);
      p[2][r] = exp2f(x2r - nm); p[3][r] = exp2f(x3r - nm);
      float rs = p[0][r] + p[1][r] + p[2][r] + p[3][r];
      #pragma unroll
      for (int mask = 1; mask < 16; mask <<= 1)
        rs += __shfl_xor(rs, mask, 64);
      lrow[r] = lrow[r] * alpha + rs;
      #pragma unroll
      for (int n4 = 0; n4 < 4; ++n4) o[n4][r] *= alpha;
    }

    // ---- P through per-wave LDS: C-layout -> A-operand layout ------------
    unsigned short* pw = &Pw[w][0];
    #pragma unroll
    for (int n4 = 0; n4 < 4; ++n4)
      #pragma unroll
      for (int r = 0; r < 4; ++r)
        pw[(quad * 4 + r) * PST + n4 * 16 + l16] = f2bfu(p[n4][r]);

    __syncthreads();                   // order Pw writes before reads

    const bf16x8 pa0 = *(const bf16x8*)&pw[l16 * PST + quad * 8];
    const bf16x8 pa1 = *(const bf16x8*)&pw[l16 * PST + 32 + quad * 8];

    // ---- O += P V (B from Vt) --------------------------------------------
    #pragma unroll
    for (int n4 = 0; n4 < 4; ++n4) {
      bf16x8 v0f = *(const bf16x8*)&Vt[(n4 * 16 + l16) * ST_ + quad * 8];
      bf16x8 v1f = *(const bf16x8*)&Vt[(n4 * 16 + l16) * ST_ + 32 + quad * 8];
      o[n4] = __builtin_amdgcn_mfma_f32_16x16x32_bf16(pa0, v0f, o[n4], 0, 0, 0);
      o[n4] = __builtin_amdgcn_mfma_f32_16x16x32_bf16(pa1, v1f, o[n4], 0, 0, 0);
    }
    __syncthreads();                   // all waves done with Ks/Vt/Pw
  }

  // ---- epilogue: divide by row sum, store f32 ----------------------------
  const size_t obase = ((size_t)h * L_ + (size_t)m * 64) * D_;
  #pragma unroll
  for (int n4 = 0; n4 < 4; ++n4) {
    #pragma unroll
    for (int r = 0; r < 4; ++r) {
      const int qrow = 16 * w + quad * 4 + r;
      out[obase + (size_t)qrow * 64 + n4 * 16 + l16] = o[n4][r] / lrow[r];
    }
  }
}

extern "C" void kernel_launch(void* const* d_in, const int* in_sizes, int n_in,
                              void* d_out, int out_size, void* d_ws, size_t ws_size,
                              hipStream_t stream) {
  const float* q = (const float*)d_in[0];
  const float* k = (const float*)d_in[1];
  const float* v = (const float*)d_in[2];
  float* out = (float*)d_out;

  fusedpool_kernel<<<H_ * NB_, 256, 0, stream>>>(q, k, v);
  center_kernel<<<H_, 256, 0, stream>>>();
  topk_kernel<<<H_ * MB_, 64, 0, stream>>>();
  attn_kernel<<<H_ * MB_, 256, 0, stream>>>(out);
}